// Round 2
// baseline (717.885 us; speedup 1.0000x reference)
//
#include <hip/hip_runtime.h>
#include <hip/hip_bf16.h>
#include <math.h>

#define EMB_DIM 4096
#define INNER   1024
#define VOCAB   32000
#define NPRED   3
#define SEQ     512
#define TOKENS  1024   // B*N = 2*512

typedef __attribute__((ext_vector_type(8))) short bf16x8;
typedef __attribute__((ext_vector_type(4))) float f32x4;

__device__ inline void gload_lds16(const void* g, void* l) {
  __builtin_amdgcn_global_load_lds(
      (const __attribute__((address_space(1))) void*)g,
      (__attribute__((address_space(3))) void*)l, 16, 0, 0);
}

__device__ inline unsigned short f2bf(float f) {
  unsigned u = __float_as_uint(f);
  u += 0x7fffu + ((u >> 16) & 1u);
  return (unsigned short)(u >> 16);
}

// ---------------- f32 -> bf16 convert, x4 vectorized (state only) ----------
__global__ void cvt_kernel(const float4* __restrict__ in, ushort4* __restrict__ out, int n4) {
  int stride = gridDim.x * blockDim.x;
  for (int i = blockIdx.x * blockDim.x + threadIdx.x; i < n4; i += stride) {
    float4 v = in[i];
    ushort4 o;
    o.x = f2bf(v.x); o.y = f2bf(v.y); o.z = f2bf(v.z); o.w = f2bf(v.w);
    out[i] = o;
  }
}

// ---------------- GEMM: C[M][N] = A[M][K](bf16) * B[N][K]^T(f32) -> f32 ----
// 128x128 tile, BK=32, 4 waves (2x2), each wave 64x64 = 4x4 frags of 16x16.
// A staged via global_load_lds (width 16); B reg-staged f32 -> bf16 on the fly.
// XCD-aware bijective swizzle, by-fastest decode (B panel stays L2-resident).
__global__ __launch_bounds__(256) void gemm_btf(const __hip_bfloat16* __restrict__ A,
                                                const float* __restrict__ B,
                                                float* __restrict__ C,
                                                int M, int N, int K) {
  __shared__ char smem[16384];
  char* As = smem;          // [128][32] bf16 = 8192 B
  char* Bs = smem + 8192;   // [128][32] bf16

  const int tid  = threadIdx.x;
  const int lane = tid & 63;
  const int wave = tid >> 6;
  const int wm = wave >> 1, wn = wave & 1;

  // XCD swizzle (nwg % 8 == 0 for all our launches; guard anyway)
  unsigned flat = blockIdx.y * gridDim.x + blockIdx.x;
  unsigned nwg = gridDim.x * gridDim.y;
  int bxi = blockIdx.x, byi = blockIdx.y;
  if ((nwg & 7u) == 0u) {
    unsigned cpx = nwg >> 3;
    unsigned swz = (flat & 7u) * cpx + (flat >> 3);
    byi = swz % gridDim.y;      // by fastest: chunk walks down a B panel
    bxi = swz / gridDim.y;
  }
  const int bm = byi * 128;
  const int bn = bxi * 128;

  // A staging: thread t covers row t>>2 (and +64), 8 bf16 at k-offset (t&3)*8
  const char*  Ag = (const char*)(A + (size_t)(bm + (tid >> 2)) * K + (tid & 3) * 8);
  const size_t rowskipA = (size_t)64 * K * 2;  // bytes
  // B staging (f32): row bn + t>>2 (and +64), 8 f32 at k-offset (t&3)*8
  const float* Bg = B + (size_t)(bn + (tid >> 2)) * K + (tid & 3) * 8;
  const size_t rowskipB = (size_t)64 * K;      // floats

  f32x4 acc[4][4] = {};

  const int fa = (wm * 64 + (lane & 15)) * 64 + (lane >> 4) * 16;
  const int fb = (wn * 64 + (lane & 15)) * 64 + (lane >> 4) * 16;

  for (int k0 = 0; k0 < K; k0 += 32) {
    // A -> LDS via async DMA
    gload_lds16(Ag,            As + tid * 16);
    gload_lds16(Ag + rowskipA, As + 4096 + tid * 16);
    Ag += 64;
    // B: f32 global -> regs -> convert -> LDS
    {
      float4 lo0 = *(const float4*)(Bg);
      float4 hi0 = *(const float4*)(Bg + 4);
      float4 lo1 = *(const float4*)(Bg + rowskipB);
      float4 hi1 = *(const float4*)(Bg + rowskipB + 4);
      Bg += 32;
      ushort s0[8] = { f2bf(lo0.x), f2bf(lo0.y), f2bf(lo0.z), f2bf(lo0.w),
                       f2bf(hi0.x), f2bf(hi0.y), f2bf(hi0.z), f2bf(hi0.w) };
      ushort s1[8] = { f2bf(lo1.x), f2bf(lo1.y), f2bf(lo1.z), f2bf(lo1.w),
                       f2bf(hi1.x), f2bf(hi1.y), f2bf(hi1.z), f2bf(hi1.w) };
      *(bf16x8*)(Bs + tid * 16)        = *(const bf16x8*)s0;
      *(bf16x8*)(Bs + 4096 + tid * 16) = *(const bf16x8*)s1;
    }
    __syncthreads();

    bf16x8 af[4], bfv[4];
#pragma unroll
    for (int m = 0; m < 4; ++m) af[m]  = *(const bf16x8*)(As + fa + m * 1024);
#pragma unroll
    for (int n = 0; n < 4; ++n) bfv[n] = *(const bf16x8*)(Bs + fb + n * 1024);
#pragma unroll
    for (int m = 0; m < 4; ++m)
#pragma unroll
      for (int n = 0; n < 4; ++n)
        acc[m][n] = __builtin_amdgcn_mfma_f32_16x16x32_bf16(af[m], bfv[n], acc[m][n], 0, 0, 0);
    __syncthreads();
  }

  // epilogue: C/D layout col = lane&15, row = (lane>>4)*4 + r
  const int r0 = bm + wm * 64 + (lane >> 4) * 4;
  const int c0 = bn + wn * 64 + (lane & 15);
#pragma unroll
  for (int m = 0; m < 4; ++m)
#pragma unroll
    for (int n = 0; n < 4; ++n) {
      float* Cp = C + (size_t)(r0 + m * 16) * N + (c0 + n * 16);
#pragma unroll
      for (int r = 0; r < 4; ++r)
        Cp[(size_t)r * N] = acc[m][n][r];
    }
}

// ---------------- fused: s = ns + alpha*z ; RMS-LN ; exact GELU ; -> bf16 ----
__global__ __launch_bounds__(256) void fuse_ln_gelu(const float* __restrict__ ns,
    const float* __restrict__ emb,   // emb_w[i] base: [VOCAB][INNER]
    const int* __restrict__ inds,    // [2][SEQ+NPRED]
    const float* __restrict__ lnw, const float* __restrict__ lnb,
    ushort4* __restrict__ out_bf16,  // [TOKENS][INNER] bf16
    int i, float alpha)
{
  const int t = blockIdx.x;          // token 0..1023
  const int b = t >> 9, n = t & 511;
  const int idx = inds[b * (SEQ + NPRED) + n + i];

  const float4* x = (const float4*)(ns + (size_t)t * INNER);
  const float4* z = (const float4*)(emb + (size_t)idx * INNER);
  const int j = threadIdx.x;         // each thread: 4 elems

  float4 xv = x[j], zv = z[j];
  float4 v;
  v.x = xv.x + alpha * zv.x;
  v.y = xv.y + alpha * zv.y;
  v.z = xv.z + alpha * zv.z;
  v.w = xv.w + alpha * zv.w;

  float ss = v.x * v.x + v.y * v.y + v.z * v.z + v.w * v.w;
#pragma unroll
  for (int o = 32; o > 0; o >>= 1) ss += __shfl_down(ss, o);
  __shared__ float red[4];
  if ((threadIdx.x & 63) == 0) red[threadIdx.x >> 6] = ss;
  __syncthreads();
  float total = red[0] + red[1] + red[2] + red[3];
  float r = rsqrtf(total * (1.0f / INNER) + 1e-6f);

  float4 wv = ((const float4*)lnw)[j];
  float4 bv = ((const float4*)lnb)[j];
  const float inv_sqrt2 = 0.70710678118654752f;
  ushort4 o;
  float y;
  y = v.x * r * wv.x + bv.x; o.x = f2bf(0.5f * y * (1.0f + erff(y * inv_sqrt2)));
  y = v.y * r * wv.y + bv.y; o.y = f2bf(0.5f * y * (1.0f + erff(y * inv_sqrt2)));
  y = v.z * r * wv.z + bv.z; o.z = f2bf(0.5f * y * (1.0f + erff(y * inv_sqrt2)));
  y = v.w * r * wv.w + bv.w; o.w = f2bf(0.5f * y * (1.0f + erff(y * inv_sqrt2)));

  out_bf16[(size_t)t * (INNER / 4) + j] = o;
}

extern "C" void kernel_launch(void* const* d_in, const int* in_sizes, int n_in,
                              void* d_out, int out_size, void* d_ws, size_t ws_size,
                              hipStream_t stream) {
  const float* state = (const float*)d_in[0];
  const int*   inds  = (const int*)d_in[1];
  const float* emb_w = (const float*)d_in[2];
  const float* proj0 = (const float*)d_in[3];
  const float* projw = (const float*)d_in[4];
  const float* headw = (const float*)d_in[5];
  const float* lnw   = (const float*)d_in[6];
  const float* lnb   = (const float*)d_in[7];
  float* out = (float*)d_out;

  char* ws = (char*)d_ws;
  __hip_bfloat16* stateA = (__hip_bfloat16*)(ws);                    // 1024*4096 bf16
  __hip_bfloat16* stateI = (__hip_bfloat16*)(ws + 8388608);          // 1024*1024 bf16
  float*          nsf    = (float*)        (ws + 10485760);          // 1024*1024 f32

  double sw = pow(0.5, 1.0 / 6.0);
  float alpha = (float)(sqrt((1.0 - sw * sw) * (INNER / 2.0)) / sw);

  // convert state (A of step 0) to bf16 once
  {
    int n4 = (int)((size_t)TOKENS * EMB_DIM / 4);
    int blocks = (n4 + 255) / 256;
    if (blocks > 4096) blocks = 4096;
    cvt_kernel<<<dim3(blocks), dim3(256), 0, stream>>>((const float4*)state, (ushort4*)stateA, n4);
  }

  for (int i = 0; i < NPRED; ++i) {
    const __hip_bfloat16* Ab = (i == 0) ? stateA : stateI;
    const float* Bw = (i == 0) ? proj0 : projw + (size_t)(i - 1) * INNER * INNER;
    int K = (i == 0) ? EMB_DIM : INNER;
    gemm_btf<<<dim3(INNER / 128, TOKENS / 128), dim3(256), 0, stream>>>(Ab, Bw, nsf, TOKENS, INNER, K);

    fuse_ln_gelu<<<dim3(TOKENS), dim3(256), 0, stream>>>(nsf,
        emb_w + (size_t)i * VOCAB * INNER, inds,
        lnw + i * INNER, lnb + i * INNER, (ushort4*)stateI, i, alpha);

    gemm_btf<<<dim3(VOCAB / 128, TOKENS / 128), dim3(256), 0, stream>>>(stateI,
        headw + (size_t)i * VOCAB * INNER,
        out + (size_t)i * TOKENS * VOCAB, TOKENS, VOCAB, INNER);
  }
}

// Round 3
// 452.023 us; speedup vs baseline: 1.5882x; 1.5882x over previous
//
#include <hip/hip_runtime.h>
#include <hip/hip_bf16.h>
#include <math.h>

#define EMB_DIM 4096
#define INNER   1024
#define VOCAB   32000
#define NPRED   3
#define SEQ     512
#define TOKENS  1024   // B*N = 2*512

typedef __attribute__((ext_vector_type(8))) short bf16x8;
typedef __attribute__((ext_vector_type(4))) float f32x4;

__device__ inline void gload_lds16(const void* g, void* l) {
  __builtin_amdgcn_global_load_lds(
      (const __attribute__((address_space(1))) void*)g,
      (__attribute__((address_space(3))) void*)l, 16, 0, 0);
}

__device__ inline unsigned short f2bf(float f) {
  unsigned u = __float_as_uint(f);
  u += 0x7fffu + ((u >> 16) & 1u);
  return (unsigned short)(u >> 16);
}

// ---------------- f32 -> bf16 convert, x4 vectorized ----------------
__global__ void cvt_kernel(const float4* __restrict__ in, ushort4* __restrict__ out, int n4) {
  int stride = gridDim.x * blockDim.x;
  for (int i = blockIdx.x * blockDim.x + threadIdx.x; i < n4; i += stride) {
    float4 v = in[i];
    ushort4 o;
    o.x = f2bf(v.x); o.y = f2bf(v.y); o.z = f2bf(v.z); o.w = f2bf(v.w);
    out[i] = o;
  }
}

// ---------------- merged: 128x128 proj GEMM (blocks 0..63) + head cvt (64..1023)
// GEMM: C[1024][1024] = A[1024][K](bf16) * Bw[1024][K]^T(bf16), m97 verified structure.
__global__ __launch_bounds__(256) void proj_cvt(const __hip_bfloat16* __restrict__ A,
                                                const __hip_bfloat16* __restrict__ Bw,
                                                float* __restrict__ C, int K,
                                                const float4* __restrict__ cvsrc,
                                                ushort4* __restrict__ cvdst, int n4) {
  if (blockIdx.x >= 64) {
    // head-weight f32 -> bf16, grid-stride over 960 blocks
    for (int i = (blockIdx.x - 64) * 256 + threadIdx.x; i < n4; i += 960 * 256) {
      float4 v = cvsrc[i];
      ushort4 o;
      o.x = f2bf(v.x); o.y = f2bf(v.y); o.z = f2bf(v.z); o.w = f2bf(v.w);
      cvdst[i] = o;
    }
    return;
  }
  __shared__ char smem[16384];
  char* As = smem;          // [128][32] bf16
  char* Bs = smem + 8192;   // [128][32] bf16

  const int tid  = threadIdx.x;
  const int lane = tid & 63;
  const int wave = tid >> 6;
  const int wm = wave >> 1, wn = wave & 1;

  const int bm = (blockIdx.x >> 3) * 128;
  const int bn = (blockIdx.x & 7) * 128;
  const int N = 1024;

  const char* Ag = (const char*)(A  + (size_t)(bm + (tid >> 2)) * K + (tid & 3) * 8);
  const char* Bg = (const char*)(Bw + (size_t)(bn + (tid >> 2)) * K + (tid & 3) * 8);
  const size_t rowskip = (size_t)64 * K * 2;

  f32x4 acc[4][4] = {};

  const int fa = (wm * 64 + (lane & 15)) * 64 + (lane >> 4) * 16;
  const int fb = (wn * 64 + (lane & 15)) * 64 + (lane >> 4) * 16;

  for (int k0 = 0; k0 < K; k0 += 32) {
    gload_lds16(Ag,           As + tid * 16);
    gload_lds16(Ag + rowskip, As + 4096 + tid * 16);
    gload_lds16(Bg,           Bs + tid * 16);
    gload_lds16(Bg + rowskip, Bs + 4096 + tid * 16);
    Ag += 64; Bg += 64;
    __syncthreads();

    bf16x8 af[4], bfv[4];
#pragma unroll
    for (int m = 0; m < 4; ++m) af[m]  = *(const bf16x8*)(As + fa + m * 1024);
#pragma unroll
    for (int n = 0; n < 4; ++n) bfv[n] = *(const bf16x8*)(Bs + fb + n * 1024);
#pragma unroll
    for (int m = 0; m < 4; ++m)
#pragma unroll
      for (int n = 0; n < 4; ++n)
        acc[m][n] = __builtin_amdgcn_mfma_f32_16x16x32_bf16(af[m], bfv[n], acc[m][n], 0, 0, 0);
    __syncthreads();
  }

  const int r0 = bm + wm * 64 + (lane >> 4) * 4;
  const int c0 = bn + wn * 64 + (lane & 15);
#pragma unroll
  for (int m = 0; m < 4; ++m)
#pragma unroll
    for (int n = 0; n < 4; ++n) {
      float* Cp = C + (size_t)(r0 + m * 16) * N + (c0 + n * 16);
#pragma unroll
      for (int r = 0; r < 4; ++r)
        Cp[(size_t)r * N] = acc[m][n][r];
    }
}

// ---------------- 256x256 head GEMM: counted-vmcnt depth-2 pipeline ----------
// C[M][N] = A[M][K](bf16) * B[N][K]^T(bf16) -> f32. BK=32, 8 waves (2Mx4N),
// per-wave 128x64 = 8x4 frags. LDS 64KB: A dbuf 2x16KB @0, B dbuf @32768.
// XOR swizzle (slot ^= (row>>1)&3) applied on BOTH global-source and read side;
// LDS dest stays linear for global_load_lds. vmcnt(4) = keep next tile in flight.
__global__ __launch_bounds__(512, 2) void gemm256(const __hip_bfloat16* __restrict__ A,
                                                  const __hip_bfloat16* __restrict__ B,
                                                  float* __restrict__ C,
                                                  int M, int N, int K) {
  __shared__ char smem[65536];
  const int tid  = threadIdx.x;
  const int lane = tid & 63;
  const int wave = tid >> 6;
  const int wm = wave >> 2;   // 0..1
  const int wn = wave & 3;    // 0..3

  // bijective chunked XCD swizzle (m204), m-fastest decode for B-panel L2 reuse
  const int MT = M >> 8;
  const int nwg = gridDim.x;
  const int o = blockIdx.x;
  const int q = nwg >> 3, r = nwg & 7;
  const int xcd = o & 7, idx = o >> 3;
  const int wg = (xcd < r ? xcd * (q + 1) : r * (q + 1) + (xcd - r) * q) + idx;
  const int bm = (wg % MT) * 256;
  const int bn = (wg / MT) * 256;

  f32x4 acc[8][4] = {};

  // frag read offsets (swizzled): row stride 64B, slot(16B) ^= (row>>1)&3
  const int sl   = (lane >> 4) ^ ((lane >> 1) & 3);
  const int aoff = (wm * 128 + (lane & 15)) * 64 + sl * 16;
  const int boff = (wn * 64  + (lane & 15)) * 64 + sl * 16;

  // stage one 256x32 bf16 tile (16KB = 1024 chunks of 16B); 512 thr x 2 chunks.
  // linear LDS dest; source slot pre-swizzled (involution of read-side XOR).
#define STAGE_T(PTR, BASEROW, LDSBASE, KT_)                                     \
  {                                                                             \
    _Pragma("unroll")                                                           \
    for (int c = 0; c < 2; ++c) {                                               \
      int chunk = c * 512 + tid;                                                \
      int row = chunk >> 2;                                                     \
      int s = (chunk & 3) ^ ((row >> 1) & 3);                                   \
      gload_lds16(PTR + (size_t)((BASEROW) + row) * K + (KT_) * 32 + s * 8,     \
                  smem + (LDSBASE) + chunk * 16);                               \
    }                                                                           \
  }

  // prologue: tiles 0 and 1
  STAGE_T(A, bm, 0,     0)
  STAGE_T(B, bn, 32768, 0)
  STAGE_T(A, bm, 16384, 1)
  STAGE_T(B, bn, 49152, 1)

  const int KT = K >> 5;
  for (int t = 0; t < KT; ++t) {
    const int b = t & 1;
    const char* Ab = smem + b * 16384;
    const char* Bb = smem + 32768 + b * 16384;

    asm volatile("s_waitcnt vmcnt(4)" ::: "memory");  // own tile-t loads done; t+1 in flight
    __builtin_amdgcn_s_barrier();                     // all waves' tile-t staged

    bf16x8 af[8], bfv[4];
#pragma unroll
    for (int m = 0; m < 8; ++m) af[m]  = *(const bf16x8*)(Ab + aoff + m * 1024);
#pragma unroll
    for (int n = 0; n < 4; ++n) bfv[n] = *(const bf16x8*)(Bb + boff + n * 1024);

    asm volatile("s_waitcnt lgkmcnt(0)" ::: "memory");  // this wave's reads drained
    __builtin_amdgcn_sched_barrier(0);
    __builtin_amdgcn_s_barrier();                       // all waves done reading buf b

    int pk = (t + 2 < KT) ? t + 2 : KT - 1;             // clamped: tail re-stage harmless
    STAGE_T(A, bm, b * 16384, pk)
    STAGE_T(B, bn, 32768 + b * 16384, pk)

    __builtin_amdgcn_s_setprio(1);
#pragma unroll
    for (int m = 0; m < 8; ++m)
#pragma unroll
      for (int n = 0; n < 4; ++n)
        acc[m][n] = __builtin_amdgcn_mfma_f32_16x16x32_bf16(af[m], bfv[n], acc[m][n], 0, 0, 0);
    __builtin_amdgcn_s_setprio(0);
    __builtin_amdgcn_sched_barrier(0);
  }
  asm volatile("s_waitcnt vmcnt(0)" ::: "memory");  // drain DMA before wave exit

  // epilogue: C/D layout col = lane&15, row = (lane>>4)*4 + rr
  const int r0 = bm + wm * 128 + (lane >> 4) * 4;
  const int c0 = bn + wn * 64 + (lane & 15);
#pragma unroll
  for (int m = 0; m < 8; ++m)
#pragma unroll
    for (int n = 0; n < 4; ++n) {
      float* Cp = C + (size_t)(r0 + m * 16) * N + (c0 + n * 16);
#pragma unroll
      for (int rr = 0; rr < 4; ++rr)
        Cp[(size_t)rr * N] = acc[m][n][rr];
    }
#undef STAGE_T
}

// ---------------- fused: s = ns + alpha*z ; RMS-LN ; exact GELU ; -> bf16 ----
__global__ __launch_bounds__(256) void fuse_ln_gelu(const float* __restrict__ ns,
    const float* __restrict__ emb,
    const int* __restrict__ inds,
    const float* __restrict__ lnw, const float* __restrict__ lnb,
    ushort4* __restrict__ out_bf16,
    int i, float alpha)
{
  const int t = blockIdx.x;
  const int b = t >> 9, n = t & 511;
  const int idx = inds[b * (SEQ + NPRED) + n + i];

  const float4* x = (const float4*)(ns + (size_t)t * INNER);
  const float4* z = (const float4*)(emb + (size_t)idx * INNER);
  const int j = threadIdx.x;

  float4 xv = x[j], zv = z[j];
  float4 v;
  v.x = xv.x + alpha * zv.x;
  v.y = xv.y + alpha * zv.y;
  v.z = xv.z + alpha * zv.z;
  v.w = xv.w + alpha * zv.w;

  float ss = v.x * v.x + v.y * v.y + v.z * v.z + v.w * v.w;
#pragma unroll
  for (int o = 32; o > 0; o >>= 1) ss += __shfl_down(ss, o);
  __shared__ float red[4];
  if ((threadIdx.x & 63) == 0) red[threadIdx.x >> 6] = ss;
  __syncthreads();
  float total = red[0] + red[1] + red[2] + red[3];
  float r = rsqrtf(total * (1.0f / INNER) + 1e-6f);

  float4 wv = ((const float4*)lnw)[j];
  float4 bv = ((const float4*)lnb)[j];
  const float inv_sqrt2 = 0.70710678118654752f;
  ushort4 o;
  float y;
  y = v.x * r * wv.x + bv.x; o.x = f2bf(0.5f * y * (1.0f + erff(y * inv_sqrt2)));
  y = v.y * r * wv.y + bv.y; o.y = f2bf(0.5f * y * (1.0f + erff(y * inv_sqrt2)));
  y = v.z * r * wv.z + bv.z; o.z = f2bf(0.5f * y * (1.0f + erff(y * inv_sqrt2)));
  y = v.w * r * wv.w + bv.w; o.w = f2bf(0.5f * y * (1.0f + erff(y * inv_sqrt2)));

  out_bf16[(size_t)t * (INNER / 4) + j] = o;
}

extern "C" void kernel_launch(void* const* d_in, const int* in_sizes, int n_in,
                              void* d_out, int out_size, void* d_ws, size_t ws_size,
                              hipStream_t stream) {
  const float* state = (const float*)d_in[0];
  const int*   inds  = (const int*)d_in[1];
  const float* emb_w = (const float*)d_in[2];
  const float* proj0 = (const float*)d_in[3];
  const float* projw = (const float*)d_in[4];
  const float* headw = (const float*)d_in[5];
  const float* lnw   = (const float*)d_in[6];
  const float* lnb   = (const float*)d_in[7];
  float* out = (float*)d_out;

  char* ws = (char*)d_ws;
  __hip_bfloat16* stateA = (__hip_bfloat16*)(ws);                    // 1024*4096 bf16
  __hip_bfloat16* stateI = (__hip_bfloat16*)(ws + 8388608);          // 1024*1024 bf16
  float*          nsf    = (float*)        (ws + 10485760);          // 1024*1024 f32
  __hip_bfloat16* p0b    = (__hip_bfloat16*)(ws + 14680064);         // 1024*4096 bf16
  __hip_bfloat16* pwb    = (__hip_bfloat16*)(ws + 23068672);         // 2*1024*1024 bf16
  __hip_bfloat16* hb     = (__hip_bfloat16*)(ws + 27262976);         // 32000*1024 bf16

  double sw = pow(0.5, 1.0 / 6.0);
  float alpha = (float)(sqrt((1.0 - sw * sw) * (INNER / 2.0)) / sw);

  auto cvt = [&](const float* src, __hip_bfloat16* dst, size_t n) {
    int n4 = (int)(n / 4);
    int blocks = (n4 + 255) / 256;
    if (blocks > 2048) blocks = 2048;
    cvt_kernel<<<dim3(blocks), dim3(256), 0, stream>>>((const float4*)src, (ushort4*)dst, n4);
  };

  // pre-convert state + proj weights (head weights convert inside proj_cvt)
  cvt(state, stateA, (size_t)TOKENS * EMB_DIM);
  cvt(proj0, p0b, (size_t)INNER * EMB_DIM);
  cvt(projw, pwb, (size_t)2 * INNER * INNER);

  for (int i = 0; i < NPRED; ++i) {
    const __hip_bfloat16* Ab = (i == 0) ? stateA : stateI;
    const __hip_bfloat16* Bb = (i == 0) ? p0b : pwb + (size_t)(i - 1) * INNER * INNER;
    int K = (i == 0) ? EMB_DIM : INNER;

    proj_cvt<<<dim3(1024), dim3(256), 0, stream>>>(Ab, Bb, nsf, K,
        (const float4*)(headw + (size_t)i * VOCAB * INNER), (ushort4*)hb,
        (int)((size_t)VOCAB * INNER / 4));

    fuse_ln_gelu<<<dim3(TOKENS), dim3(256), 0, stream>>>(nsf,
        emb_w + (size_t)i * VOCAB * INNER, inds,
        lnw + i * INNER, lnb + i * INNER, (ushort4*)stateI, i, alpha);

    gemm256<<<dim3(500), dim3(512), 0, stream>>>(stateI, hb,
        out + (size_t)i * TOKENS * VOCAB, TOKENS, VOCAB, INNER);
  }
}

// Round 4
// 439.054 us; speedup vs baseline: 1.6351x; 1.0295x over previous
//
#include <hip/hip_runtime.h>
#include <hip/hip_bf16.h>
#include <math.h>

#define EMB_DIM 4096
#define INNER   1024
#define VOCAB   32000
#define NPRED   3
#define SEQ     512
#define TOKENS  1024   // B*N = 2*512

typedef __attribute__((ext_vector_type(8))) short bf16x8;
typedef __attribute__((ext_vector_type(4))) float f32x4;

__device__ inline void gload_lds16(const void* g, void* l) {
  __builtin_amdgcn_global_load_lds(
      (const __attribute__((address_space(1))) void*)g,
      (__attribute__((address_space(3))) void*)l, 16, 0, 0);
}

__device__ inline unsigned short f2bf(float f) {
  unsigned u = __float_as_uint(f);
  u += 0x7fffu + ((u >> 16) & 1u);
  return (unsigned short)(u >> 16);
}

// ---------------- f32 -> bf16 convert, x4 vectorized ----------------
__global__ void cvt_kernel(const float4* __restrict__ in, ushort4* __restrict__ out, int n4) {
  int stride = gridDim.x * blockDim.x;
  for (int i = blockIdx.x * blockDim.x + threadIdx.x; i < n4; i += stride) {
    float4 v = in[i];
    ushort4 o;
    o.x = f2bf(v.x); o.y = f2bf(v.y); o.z = f2bf(v.z); o.w = f2bf(v.w);
    out[i] = o;
  }
}

// ---------------- merged: 128x128 proj GEMM (blocks 0..63) + head cvt (64..1023)
__global__ __launch_bounds__(256) void proj_cvt(const __hip_bfloat16* __restrict__ A,
                                                const __hip_bfloat16* __restrict__ Bw,
                                                float* __restrict__ C, int K,
                                                const float4* __restrict__ cvsrc,
                                                ushort4* __restrict__ cvdst, int n4) {
  if (blockIdx.x >= 64) {
    for (int i = (blockIdx.x - 64) * 256 + threadIdx.x; i < n4; i += 960 * 256) {
      float4 v = cvsrc[i];
      ushort4 o;
      o.x = f2bf(v.x); o.y = f2bf(v.y); o.z = f2bf(v.z); o.w = f2bf(v.w);
      cvdst[i] = o;
    }
    return;
  }
  __shared__ char smem[16384];
  char* As = smem;          // [128][32] bf16
  char* Bs = smem + 8192;   // [128][32] bf16

  const int tid  = threadIdx.x;
  const int lane = tid & 63;
  const int wave = tid >> 6;
  const int wm = wave >> 1, wn = wave & 1;

  const int bm = (blockIdx.x >> 3) * 128;
  const int bn = (blockIdx.x & 7) * 128;
  const int N = 1024;

  const char* Ag = (const char*)(A  + (size_t)(bm + (tid >> 2)) * K + (tid & 3) * 8);
  const char* Bg = (const char*)(Bw + (size_t)(bn + (tid >> 2)) * K + (tid & 3) * 8);
  const size_t rowskip = (size_t)64 * K * 2;

  f32x4 acc[4][4] = {};

  const int fa = (wm * 64 + (lane & 15)) * 64 + (lane >> 4) * 16;
  const int fb = (wn * 64 + (lane & 15)) * 64 + (lane >> 4) * 16;

  for (int k0 = 0; k0 < K; k0 += 32) {
    gload_lds16(Ag,           As + tid * 16);
    gload_lds16(Ag + rowskip, As + 4096 + tid * 16);
    gload_lds16(Bg,           Bs + tid * 16);
    gload_lds16(Bg + rowskip, Bs + 4096 + tid * 16);
    Ag += 64; Bg += 64;
    __syncthreads();

    bf16x8 af[4], bfv[4];
#pragma unroll
    for (int m = 0; m < 4; ++m) af[m]  = *(const bf16x8*)(As + fa + m * 1024);
#pragma unroll
    for (int n = 0; n < 4; ++n) bfv[n] = *(const bf16x8*)(Bs + fb + n * 1024);
#pragma unroll
    for (int m = 0; m < 4; ++m)
#pragma unroll
      for (int n = 0; n < 4; ++n)
        acc[m][n] = __builtin_amdgcn_mfma_f32_16x16x32_bf16(af[m], bfv[n], acc[m][n], 0, 0, 0);
    __syncthreads();
  }

  const int r0 = bm + wm * 64 + (lane >> 4) * 4;
  const int c0 = bn + wn * 64 + (lane & 15);
#pragma unroll
  for (int m = 0; m < 4; ++m)
#pragma unroll
    for (int n = 0; n < 4; ++n) {
      float* Cp = C + (size_t)(r0 + m * 16) * N + (c0 + n * 16);
#pragma unroll
      for (int r = 0; r < 4; ++r)
        Cp[(size_t)r * N] = acc[m][n][r];
    }
}

// ---------------- 256x256 head GEMM: ring-4 fine-phased counted-vmcnt -------
// C[M][N] = A[M][K](bf16) * B[N][K]^T(bf16) -> f32. BK=32, 8 waves (2Mx4N),
// per-wave 128x64 = 8x4 frags. LDS 128KB: A ring-4 @0 (4x16KB), B ring-4 @65536.
// Stage tile t+3 while computing tile t; vmcnt(8) = tiles t+1,t+2 in flight.
// One barrier per K-tile; 2 phases of {ds_read | stage | lgkmcnt | 16 MFMA}.
__global__ __launch_bounds__(512, 2) void gemm256(const __hip_bfloat16* __restrict__ A,
                                                  const __hip_bfloat16* __restrict__ B,
                                                  float* __restrict__ C,
                                                  int M, int N, int K) {
  __shared__ char smem[131072];
  const int tid  = threadIdx.x;
  const int lane = tid & 63;
  const int wave = tid >> 6;
  const int wm = wave >> 2;   // 0..1
  const int wn = wave & 3;    // 0..3

  // bijective chunked XCD swizzle (m204), m-fastest decode for B-panel L2 reuse
  const int MT = M >> 8;
  const int nwg = gridDim.x;
  const int o = blockIdx.x;
  const int q = nwg >> 3, r = nwg & 7;
  const int xcd = o & 7, idx = o >> 3;
  const int wg = (xcd < r ? xcd * (q + 1) : r * (q + 1) + (xcd - r) * q) + idx;
  const int bm = (wg % MT) * 256;
  const int bn = (wg / MT) * 256;

  f32x4 acc[8][4] = {};

  // frag read offsets (swizzled): row stride 64B, slot(16B) ^= (row>>1)&3
  const int sl   = (lane >> 4) ^ ((lane >> 1) & 3);
  const int aoff = (wm * 128 + (lane & 15)) * 64 + sl * 16;
  const int boff = (wn * 64  + (lane & 15)) * 64 + sl * 16;

  // stage one 256x32 bf16 tile (16KB = 1024 chunks of 16B); 512 thr x 2 chunks.
  // linear LDS dest; source slot pre-swizzled (involution of read-side XOR).
#define STAGE_T(PTR, BASEROW, LDSBASE, KT_)                                     \
  {                                                                             \
    _Pragma("unroll")                                                           \
    for (int c = 0; c < 2; ++c) {                                               \
      int chunk = c * 512 + tid;                                                \
      int row = chunk >> 2;                                                     \
      int s = (chunk & 3) ^ ((row >> 1) & 3);                                   \
      gload_lds16(PTR + (size_t)((BASEROW) + row) * K + (KT_) * 32 + s * 8,     \
                  smem + (LDSBASE) + chunk * 16);                               \
    }                                                                           \
  }

  // prologue: stage tiles 0,1,2 into ring slots 0,1,2 (12 loads in flight)
  STAGE_T(A, bm, 0,             0)
  STAGE_T(B, bn, 65536,         0)
  STAGE_T(A, bm, 16384,         1)
  STAGE_T(B, bn, 65536 + 16384, 1)
  STAGE_T(A, bm, 32768,         2)
  STAGE_T(B, bn, 65536 + 32768, 2)

  const int KT = K >> 5;
  for (int t = 0; t < KT; ++t) {
    const int bc = (t & 3) * 16384;        // compute buffer
    const int bs = ((t + 3) & 3) * 16384;  // stage target (read by t-1, now free)
    const char* Ab = smem + bc;
    const char* Bb = smem + 65536 + bc;

    // tile t's 4 loads (issued at t-3 / prologue) are older than the 8 newest
    // (t+1, t+2) -> vmcnt(8) forces them landed while keeping 8 in flight.
    asm volatile("s_waitcnt vmcnt(8)" ::: "memory");
    __builtin_amdgcn_s_barrier();          // all waves: tile t staged, t-1 reads done

    const int pk = (t + 3 < KT) ? t + 3 : KT - 1;  // tail clamp keeps counts uniform

    // ---- phase 0: m-frags 0..3, all bf; stage A-half of tile t+3 ----
    bf16x8 af0[4], bfv[4];
#pragma unroll
    for (int m = 0; m < 4; ++m) af0[m] = *(const bf16x8*)(Ab + aoff + m * 1024);
#pragma unroll
    for (int n = 0; n < 4; ++n) bfv[n] = *(const bf16x8*)(Bb + boff + n * 1024);
    STAGE_T(A, bm, bs, pk)
    asm volatile("s_waitcnt lgkmcnt(0)" ::: "memory");
    __builtin_amdgcn_sched_barrier(0);
    __builtin_amdgcn_s_setprio(1);
#pragma unroll
    for (int m = 0; m < 4; ++m)
#pragma unroll
      for (int n = 0; n < 4; ++n)
        acc[m][n] = __builtin_amdgcn_mfma_f32_16x16x32_bf16(af0[m], bfv[n], acc[m][n], 0, 0, 0);
    __builtin_amdgcn_s_setprio(0);

    // ---- phase 1: m-frags 4..7 (bf reused); stage B-half of tile t+3 ----
    bf16x8 af1[4];
#pragma unroll
    for (int m = 0; m < 4; ++m) af1[m] = *(const bf16x8*)(Ab + aoff + (m + 4) * 1024);
    STAGE_T(B, bn, 65536 + bs, pk)
    asm volatile("s_waitcnt lgkmcnt(0)" ::: "memory");
    __builtin_amdgcn_sched_barrier(0);
    __builtin_amdgcn_s_setprio(1);
#pragma unroll
    for (int m = 0; m < 4; ++m)
#pragma unroll
      for (int n = 0; n < 4; ++n)
        acc[m + 4][n] = __builtin_amdgcn_mfma_f32_16x16x32_bf16(af1[m], bfv[n], acc[m + 4][n], 0, 0, 0);
    __builtin_amdgcn_s_setprio(0);
    __builtin_amdgcn_sched_barrier(0);
  }
  asm volatile("s_waitcnt vmcnt(0)" ::: "memory");  // drain DMA before wave exit

  // epilogue: C/D layout col = lane&15, row = (lane>>4)*4 + rr
  const int r0 = bm + wm * 128 + (lane >> 4) * 4;
  const int c0 = bn + wn * 64 + (lane & 15);
#pragma unroll
  for (int m = 0; m < 8; ++m)
#pragma unroll
    for (int n = 0; n < 4; ++n) {
      float* Cp = C + (size_t)(r0 + m * 16) * N + (c0 + n * 16);
#pragma unroll
      for (int rr = 0; rr < 4; ++rr)
        Cp[(size_t)rr * N] = acc[m][n][rr];
    }
#undef STAGE_T
}

// ---------------- fused: s = ns + alpha*z ; RMS-LN ; exact GELU ; -> bf16 ----
__global__ __launch_bounds__(256) void fuse_ln_gelu(const float* __restrict__ ns,
    const float* __restrict__ emb,
    const int* __restrict__ inds,
    const float* __restrict__ lnw, const float* __restrict__ lnb,
    ushort4* __restrict__ out_bf16,
    int i, float alpha)
{
  const int t = blockIdx.x;
  const int b = t >> 9, n = t & 511;
  const int idx = inds[b * (SEQ + NPRED) + n + i];

  const float4* x = (const float4*)(ns + (size_t)t * INNER);
  const float4* z = (const float4*)(emb + (size_t)idx * INNER);
  const int j = threadIdx.x;

  float4 xv = x[j], zv = z[j];
  float4 v;
  v.x = xv.x + alpha * zv.x;
  v.y = xv.y + alpha * zv.y;
  v.z = xv.z + alpha * zv.z;
  v.w = xv.w + alpha * zv.w;

  float ss = v.x * v.x + v.y * v.y + v.z * v.z + v.w * v.w;
#pragma unroll
  for (int o = 32; o > 0; o >>= 1) ss += __shfl_down(ss, o);
  __shared__ float red[4];
  if ((threadIdx.x & 63) == 0) red[threadIdx.x >> 6] = ss;
  __syncthreads();
  float total = red[0] + red[1] + red[2] + red[3];
  float r = rsqrtf(total * (1.0f / INNER) + 1e-6f);

  float4 wv = ((const float4*)lnw)[j];
  float4 bv = ((const float4*)lnb)[j];
  const float inv_sqrt2 = 0.70710678118654752f;
  ushort4 o;
  float y;
  y = v.x * r * wv.x + bv.x; o.x = f2bf(0.5f * y * (1.0f + erff(y * inv_sqrt2)));
  y = v.y * r * wv.y + bv.y; o.y = f2bf(0.5f * y * (1.0f + erff(y * inv_sqrt2)));
  y = v.z * r * wv.z + bv.z; o.z = f2bf(0.5f * y * (1.0f + erff(y * inv_sqrt2)));
  y = v.w * r * wv.w + bv.w; o.w = f2bf(0.5f * y * (1.0f + erff(y * inv_sqrt2)));

  out_bf16[(size_t)t * (INNER / 4) + j] = o;
}

extern "C" void kernel_launch(void* const* d_in, const int* in_sizes, int n_in,
                              void* d_out, int out_size, void* d_ws, size_t ws_size,
                              hipStream_t stream) {
  const float* state = (const float*)d_in[0];
  const int*   inds  = (const int*)d_in[1];
  const float* emb_w = (const float*)d_in[2];
  const float* proj0 = (const float*)d_in[3];
  const float* projw = (const float*)d_in[4];
  const float* headw = (const float*)d_in[5];
  const float* lnw   = (const float*)d_in[6];
  const float* lnb   = (const float*)d_in[7];
  float* out = (float*)d_out;

  char* ws = (char*)d_ws;
  __hip_bfloat16* stateA = (__hip_bfloat16*)(ws);                    // 1024*4096 bf16
  __hip_bfloat16* stateI = (__hip_bfloat16*)(ws + 8388608);          // 1024*1024 bf16
  float*          nsf    = (float*)        (ws + 10485760);          // 1024*1024 f32
  __hip_bfloat16* p0b    = (__hip_bfloat16*)(ws + 14680064);         // 1024*4096 bf16
  __hip_bfloat16* pwb    = (__hip_bfloat16*)(ws + 23068672);         // 2*1024*1024 bf16
  __hip_bfloat16* hb     = (__hip_bfloat16*)(ws + 27262976);         // 32000*1024 bf16

  double sw = pow(0.5, 1.0 / 6.0);
  float alpha = (float)(sqrt((1.0 - sw * sw) * (INNER / 2.0)) / sw);

  auto cvt = [&](const float* src, __hip_bfloat16* dst, size_t n) {
    int n4 = (int)(n / 4);
    int blocks = (n4 + 255) / 256;
    if (blocks > 2048) blocks = 2048;
    cvt_kernel<<<dim3(blocks), dim3(256), 0, stream>>>((const float4*)src, (ushort4*)dst, n4);
  };

  // pre-convert state + proj weights (head weights convert inside proj_cvt)
  cvt(state, stateA, (size_t)TOKENS * EMB_DIM);
  cvt(proj0, p0b, (size_t)INNER * EMB_DIM);
  cvt(projw, pwb, (size_t)2 * INNER * INNER);

  for (int i = 0; i < NPRED; ++i) {
    const __hip_bfloat16* Ab = (i == 0) ? stateA : stateI;
    const __hip_bfloat16* Bb = (i == 0) ? p0b : pwb + (size_t)(i - 1) * INNER * INNER;
    int K = (i == 0) ? EMB_DIM : INNER;

    proj_cvt<<<dim3(1024), dim3(256), 0, stream>>>(Ab, Bb, nsf, K,
        (const float4*)(headw + (size_t)i * VOCAB * INNER), (ushort4*)hb,
        (int)((size_t)VOCAB * INNER / 4));

    fuse_ln_gelu<<<dim3(TOKENS), dim3(256), 0, stream>>>(nsf,
        emb_w + (size_t)i * VOCAB * INNER, inds,
        lnw + i * INNER, lnb + i * INNER, (ushort4*)stateI, i, alpha);

    gemm256<<<dim3(500), dim3(512), 0, stream>>>(stateI, hb,
        out + (size_t)i * TOKENS * VOCAB, TOKENS, VOCAB, INNER);
  }
}